// Round 1
// baseline (224.693 us; speedup 1.0000x reference)
//
#include <hip/hip_runtime.h>
#include <math.h>

// Problem constants
#define NMAPS   7680   // (BS*NUM_CAMS=384) * N_JOINTS=20
#define BSZ     64
#define NCAMS   6
#define NJ      20

// Output layout (flat float32, reference return order)
#define OFF_KP3D 0        // (64,20,3)   = 3840
#define OFF_RES  3840     // (64,20)     = 1280
#define OFF_KPC  5120     // (64,6,20,3) = 23040
#define OFF_KPH  28160    // (64,6,20,3) = 23040

__device__ __forceinline__ float waveMax(float v) {
#pragma unroll
    for (int off = 32; off > 0; off >>= 1)
        v = fmaxf(v, __shfl_down(v, off, 64));
    return v;
}

__device__ __forceinline__ double waveSum(double v) {
#pragma unroll
    for (int off = 32; off > 0; off >>= 1)
        v += __shfl_down(v, off, 64);
    return v;
}

// One block per (n, j) heatmap of 64*64=4096 floats.
// Computes soft-argmax x, y and confidence = 1/sum(exp(h - hmax)).
__global__ __launch_bounds__(256) void kp_kernel(const float* __restrict__ hm,
                                                 float* __restrict__ out) {
    const int b = blockIdx.x;       // map index = n*20 + j
    const int t = threadIdx.x;      // 0..255
    const float4* base = (const float4*)(hm + (size_t)b * 4096);

    float4 v[4];
#pragma unroll
    for (int i = 0; i < 4; i++) v[i] = base[t + 256 * i];

    // Pass 1: block max
    float m = v[0].x;
#pragma unroll
    for (int i = 0; i < 4; i++)
        m = fmaxf(m, fmaxf(fmaxf(v[i].x, v[i].y), fmaxf(v[i].z, v[i].w)));

    __shared__ float  smax[4];
    __shared__ double sred[3][4];
    const int wave = t >> 6, lane = t & 63;

    float wm = waveMax(m);
    if (lane == 0) smax[wave] = wm;
    __syncthreads();
    const float gmax = fmaxf(fmaxf(smax[0], smax[1]), fmaxf(smax[2], smax[3]));
    const float hmax = 100.0f * gmax;

    // Pass 2: sum(e), sum(e*col), sum(e*row) in fp64 (order-insensitive)
    double se = 0.0, sx = 0.0, sy = 0.0;
#pragma unroll
    for (int i = 0; i < 4; i++) {
        const int idx0 = (t + 256 * i) * 4;
        const float vals[4] = {v[i].x, v[i].y, v[i].z, v[i].w};
#pragma unroll
        for (int k = 0; k < 4; k++) {
            const float e = expf(100.0f * vals[k] - hmax);
            const int idx = idx0 + k;
            se += (double)e;
            sx += (double)e * (double)(idx & 63);   // col -> x
            sy += (double)e * (double)(idx >> 6);   // row -> y
        }
    }
    se = waveSum(se); sx = waveSum(sx); sy = waveSum(sy);
    if (lane == 0) { sred[0][wave] = se; sred[1][wave] = sx; sred[2][wave] = sy; }
    __syncthreads();

    if (t == 0) {
        const double SE = sred[0][0] + sred[0][1] + sred[0][2] + sred[0][3];
        const double SX = sred[1][0] + sred[1][1] + sred[1][2] + sred[1][3];
        const double SY = sred[2][0] + sred[2][1] + sred[2][2] + sred[2][3];
        const float x    = (float)(SX / SE);
        const float y    = (float)(SY / SE);
        const float conf = (float)(1.0 / SE);   // max(softmax)/sum(softmax)
        const int o = b * 3;
        out[OFF_KPH + o + 0] = x;
        out[OFF_KPH + o + 1] = y;
        out[OFF_KPH + o + 2] = conf;
        out[OFF_KPC + o + 0] = 4.0f * x;        // * (H_IMG/H_MAP)
        out[OFF_KPC + o + 1] = 4.0f * y;        // * (W_IMG/W_MAP)
        out[OFF_KPC + o + 2] = conf;
    }
}

// One thread per (bs, j): build 12x4 A, eigensolve A^T A (fp64 Jacobi),
// null vector -> kp_3d and residual.
__global__ __launch_bounds__(256) void tri_kernel(const float* __restrict__ proj,
                                                  const float* __restrict__ confin,
                                                  float* __restrict__ out) {
    const int t = blockIdx.x * blockDim.x + threadIdx.x;
    if (t >= BSZ * NJ) return;
    const int bs = t / NJ, j = t % NJ;

    // Normalized per-camera confidences: c/sum + 1e-5
    float cn[NCAMS];
    float csum = 0.0f;
#pragma unroll
    for (int c = 0; c < NCAMS; c++) {
        cn[c] = confin[(bs * NCAMS + c) * NJ + j];
        csum += cn[c];
    }
#pragma unroll
    for (int c = 0; c < NCAMS; c++) cn[c] = cn[c] / csum + 1e-5f;

    // A[(cam*2+r)][k] = (P[cam][2][k]*pt_r - P[cam][r][k]) * cn[cam]  (fp32, as ref)
    float A[12][4];
#pragma unroll
    for (int c = 0; c < NCAMS; c++) {
        const float* P = proj + ((size_t)bs * NCAMS + c) * 12;
        const int kidx = OFF_KPC + ((bs * NCAMS + c) * NJ + j) * 3;
        const float px = out[kidx + 0];
        const float py = out[kidx + 1];
#pragma unroll
        for (int k = 0; k < 4; k++) {
            const float r2 = P[8 + k];
            A[c * 2 + 0][k] = (r2 * px - P[k])     * cn[c];
            A[c * 2 + 1][k] = (r2 * py - P[4 + k]) * cn[c];
        }
    }

    // M = A^T A in fp64
    double M[4][4], V[4][4];
#pragma unroll
    for (int a = 0; a < 4; a++)
#pragma unroll
        for (int b2 = a; b2 < 4; b2++) {
            double s = 0.0;
#pragma unroll
            for (int n = 0; n < 12; n++) s += (double)A[n][a] * (double)A[n][b2];
            M[a][b2] = s; M[b2][a] = s;
        }
#pragma unroll
    for (int a = 0; a < 4; a++)
#pragma unroll
        for (int b2 = 0; b2 < 4; b2++) V[a][b2] = (a == b2) ? 1.0 : 0.0;

    // Cyclic Jacobi, 10 sweeps (4x4 converges quadratically; overkill is cheap)
    for (int sweep = 0; sweep < 10; sweep++) {
#pragma unroll
        for (int p = 0; p < 3; p++)
#pragma unroll
            for (int q2 = p + 1; q2 < 4; q2++) {
                const double apq = M[p][q2];
                if (fabs(apq) < 1e-300) continue;
                const double tau = (M[q2][q2] - M[p][p]) / (2.0 * apq);
                const double tt  = (tau >= 0.0 ? 1.0 : -1.0) /
                                   (fabs(tau) + sqrt(1.0 + tau * tau));
                const double c   = 1.0 / sqrt(1.0 + tt * tt);
                const double s   = tt * c;
#pragma unroll
                for (int k = 0; k < 4; k++) {          // right-mult columns p,q
                    const double mkp = M[k][p], mkq = M[k][q2];
                    M[k][p]  = c * mkp - s * mkq;
                    M[k][q2] = s * mkp + c * mkq;
                }
#pragma unroll
                for (int k = 0; k < 4; k++) {          // left-mult rows p,q
                    const double mpk = M[p][k], mqk = M[q2][k];
                    M[p][k]  = c * mpk - s * mqk;
                    M[q2][k] = s * mpk + c * mqk;
                }
#pragma unroll
                for (int k = 0; k < 4; k++) {          // accumulate eigenvectors
                    const double vkp = V[k][p], vkq = V[k][q2];
                    V[k][p]  = c * vkp - s * vkq;
                    V[k][q2] = s * vkp + c * vkq;
                }
            }
    }

    // Min-eigenvalue column = homogeneous solution (sign-free: outputs invariant)
    int mi = 0;
#pragma unroll
    for (int i = 1; i < 4; i++)
        if (M[i][i] < M[mi][mi]) mi = i;
    const double h0 = V[0][mi], h1 = V[1][mi], h2 = V[2][mi], h3 = V[3][mi];

    out[OFF_KP3D + t * 3 + 0] = (float)(h0 / h3);
    out[OFF_KP3D + t * 3 + 1] = (float)(h1 / h3);
    out[OFF_KP3D + t * 3 + 2] = (float)(h2 / h3);

    const float hf0 = (float)h0, hf1 = (float)h1, hf2 = (float)h2, hf3 = (float)h3;
    float res = 0.0f;
#pragma unroll
    for (int n = 0; n < 12; n++)
        res += fabsf(A[n][0] * hf0 + A[n][1] * hf1 + A[n][2] * hf2 + A[n][3] * hf3);
    out[OFF_RES + t] = res;
}

extern "C" void kernel_launch(void* const* d_in, const int* in_sizes, int n_in,
                              void* d_out, int out_size, void* d_ws, size_t ws_size,
                              hipStream_t stream) {
    const float* heatmap = (const float*)d_in[0];   // (384,20,64,64)
    const float* proj    = (const float*)d_in[1];   // (64,6,3,4)
    const float* confid  = (const float*)d_in[2];   // (384,20)
    float* out = (float*)d_out;                     // 51200 floats

    hipLaunchKernelGGL(kp_kernel, dim3(NMAPS), dim3(256), 0, stream, heatmap, out);
    hipLaunchKernelGGL(tri_kernel, dim3((BSZ * NJ + 255) / 256), dim3(256), 0, stream,
                       proj, confid, out);
}

// Round 3
// 194.906 us; speedup vs baseline: 1.1528x; 1.1528x over previous
//
#include <hip/hip_runtime.h>
#include <math.h>

// Problem constants
#define NMAPS   7680   // (BS*NUM_CAMS=384) * N_JOINTS=20
#define BSZ     64
#define NCAMS   6
#define NJ      20

// Output layout (flat float32, reference return order)
#define OFF_KP3D 0        // (64,20,3)   = 3840
#define OFF_RES  3840     // (64,20)     = 1280
#define OFF_KPC  5120     // (64,6,20,3) = 23040
#define OFF_KPH  28160    // (64,6,20,3) = 23040

// Native vector type — __builtin_nontemporal_load requires scalar/native-vector,
// not HIP_vector_type structs.
typedef float floatx4 __attribute__((ext_vector_type(4)));

__device__ __forceinline__ float waveMax(float v) {
#pragma unroll
    for (int off = 32; off > 0; off >>= 1)
        v = fmaxf(v, __shfl_down(v, off, 64));
    return v;
}

__device__ __forceinline__ double waveSum(double v) {
#pragma unroll
    for (int off = 32; off > 0; off >>= 1)
        v += __shfl_down(v, off, 64);
    return v;
}

// One block per (n, j) heatmap of 64*64=4096 floats.
// Computes soft-argmax x, y and confidence = 1/sum(exp(h - hmax)).
__global__ __launch_bounds__(256) void kp_kernel(const float* __restrict__ hm,
                                                 float* __restrict__ out) {
    const int b = blockIdx.x;       // map index = n*20 + j
    const int t = threadIdx.x;      // 0..255
    const floatx4* base = (const floatx4*)(hm + (size_t)b * 4096);

    // Read-once stream: nontemporal so we don't pollute L2/L3.
    floatx4 v[4];
#pragma unroll
    for (int i = 0; i < 4; i++) v[i] = __builtin_nontemporal_load(&base[t + 256 * i]);

    // Pass 1: block max (in-register)
    float m = v[0].x;
#pragma unroll
    for (int i = 0; i < 4; i++)
        m = fmaxf(m, fmaxf(fmaxf(v[i].x, v[i].y), fmaxf(v[i].z, v[i].w)));

    __shared__ float  smax[4];
    __shared__ double sred[3][4];
    const int wave = t >> 6, lane = t & 63;

    float wm = waveMax(m);
    if (lane == 0) smax[wave] = wm;
    __syncthreads();
    const float gmax = fmaxf(fmaxf(smax[0], smax[1]), fmaxf(smax[2], smax[3]));
    const float hmax = 100.0f * gmax;

    // Pass 2: sum(e), sum(e*col), sum(e*row) in fp64 (order-insensitive)
    double se = 0.0, sx = 0.0, sy = 0.0;
#pragma unroll
    for (int i = 0; i < 4; i++) {
        const int idx0 = (t + 256 * i) * 4;
        const float vals[4] = {v[i].x, v[i].y, v[i].z, v[i].w};
#pragma unroll
        for (int k = 0; k < 4; k++) {
            const float e = expf(100.0f * vals[k] - hmax);
            const int idx = idx0 + k;
            se += (double)e;
            sx += (double)e * (double)(idx & 63);   // col -> x
            sy += (double)e * (double)(idx >> 6);   // row -> y
        }
    }
    se = waveSum(se); sx = waveSum(sx); sy = waveSum(sy);
    if (lane == 0) { sred[0][wave] = se; sred[1][wave] = sx; sred[2][wave] = sy; }
    __syncthreads();

    if (t == 0) {
        const double SE = sred[0][0] + sred[0][1] + sred[0][2] + sred[0][3];
        const double SX = sred[1][0] + sred[1][1] + sred[1][2] + sred[1][3];
        const double SY = sred[2][0] + sred[2][1] + sred[2][2] + sred[2][3];
        const float x    = (float)(SX / SE);
        const float y    = (float)(SY / SE);
        const float conf = (float)(1.0 / SE);   // max(softmax)/sum(softmax)
        const int o = b * 3;
        out[OFF_KPH + o + 0] = x;
        out[OFF_KPH + o + 1] = y;
        out[OFF_KPH + o + 2] = conf;
        out[OFF_KPC + o + 0] = 4.0f * x;        // * (H_IMG/H_MAP)
        out[OFF_KPC + o + 1] = 4.0f * y;        // * (W_IMG/W_MAP)
        out[OFF_KPC + o + 2] = conf;
    }
}

// One thread per (bs, j): build 12x4 A, eigensolve A^T A (fp64 Jacobi),
// null vector -> kp_3d and residual.
__global__ __launch_bounds__(256) void tri_kernel(const float* __restrict__ proj,
                                                  const float* __restrict__ confin,
                                                  float* __restrict__ out) {
    const int t = blockIdx.x * blockDim.x + threadIdx.x;
    if (t >= BSZ * NJ) return;
    const int bs = t / NJ, j = t % NJ;

    // Normalized per-camera confidences: c/sum + 1e-5
    float cn[NCAMS];
    float csum = 0.0f;
#pragma unroll
    for (int c = 0; c < NCAMS; c++) {
        cn[c] = confin[(bs * NCAMS + c) * NJ + j];
        csum += cn[c];
    }
#pragma unroll
    for (int c = 0; c < NCAMS; c++) cn[c] = cn[c] / csum + 1e-5f;

    // A[(cam*2+r)][k] = (P[cam][2][k]*pt_r - P[cam][r][k]) * cn[cam]  (fp32, as ref)
    float A[12][4];
#pragma unroll
    for (int c = 0; c < NCAMS; c++) {
        const float* P = proj + ((size_t)bs * NCAMS + c) * 12;
        const int kidx = OFF_KPC + ((bs * NCAMS + c) * NJ + j) * 3;
        const float px = out[kidx + 0];
        const float py = out[kidx + 1];
#pragma unroll
        for (int k = 0; k < 4; k++) {
            const float r2 = P[8 + k];
            A[c * 2 + 0][k] = (r2 * px - P[k])     * cn[c];
            A[c * 2 + 1][k] = (r2 * py - P[4 + k]) * cn[c];
        }
    }

    // M = A^T A in fp64
    double M[4][4], V[4][4];
    double diagmax = 0.0;
#pragma unroll
    for (int a = 0; a < 4; a++)
#pragma unroll
        for (int b2 = a; b2 < 4; b2++) {
            double s = 0.0;
#pragma unroll
            for (int n = 0; n < 12; n++) s += (double)A[n][a] * (double)A[n][b2];
            M[a][b2] = s; M[b2][a] = s;
            if (a == b2) diagmax = fmax(diagmax, fabs(s));
        }
#pragma unroll
    for (int a = 0; a < 4; a++)
#pragma unroll
        for (int b2 = 0; b2 < 4; b2++) V[a][b2] = (a == b2) ? 1.0 : 0.0;

    // Cyclic Jacobi, 6 sweeps (4x4 off-diag hits fp64 eps in ~4; 6 = margin).
    // Skip rotations whose off-diag is already negligible vs the matrix scale.
    const double skip_tol = diagmax * 1e-18;
    for (int sweep = 0; sweep < 6; sweep++) {
#pragma unroll
        for (int p = 0; p < 3; p++)
#pragma unroll
            for (int q2 = p + 1; q2 < 4; q2++) {
                const double apq = M[p][q2];
                if (fabs(apq) <= skip_tol) continue;
                const double tau = (M[q2][q2] - M[p][p]) / (2.0 * apq);
                const double tt  = (tau >= 0.0 ? 1.0 : -1.0) /
                                   (fabs(tau) + sqrt(1.0 + tau * tau));
                const double c   = 1.0 / sqrt(1.0 + tt * tt);
                const double s   = tt * c;
#pragma unroll
                for (int k = 0; k < 4; k++) {          // right-mult columns p,q
                    const double mkp = M[k][p], mkq = M[k][q2];
                    M[k][p]  = c * mkp - s * mkq;
                    M[k][q2] = s * mkp + c * mkq;
                }
#pragma unroll
                for (int k = 0; k < 4; k++) {          // left-mult rows p,q
                    const double mpk = M[p][k], mqk = M[q2][k];
                    M[p][k]  = c * mpk - s * mqk;
                    M[q2][k] = s * mpk + c * mqk;
                }
#pragma unroll
                for (int k = 0; k < 4; k++) {          // accumulate eigenvectors
                    const double vkp = V[k][p], vkq = V[k][q2];
                    V[k][p]  = c * vkp - s * vkq;
                    V[k][q2] = s * vkp + c * vkq;
                }
            }
    }

    // Min-eigenvalue column = homogeneous solution (sign-free: outputs invariant)
    int mi = 0;
#pragma unroll
    for (int i = 1; i < 4; i++)
        if (M[i][i] < M[mi][mi]) mi = i;
    const double h0 = V[0][mi], h1 = V[1][mi], h2 = V[2][mi], h3 = V[3][mi];

    out[OFF_KP3D + t * 3 + 0] = (float)(h0 / h3);
    out[OFF_KP3D + t * 3 + 1] = (float)(h1 / h3);
    out[OFF_KP3D + t * 3 + 2] = (float)(h2 / h3);

    const float hf0 = (float)h0, hf1 = (float)h1, hf2 = (float)h2, hf3 = (float)h3;
    float res = 0.0f;
#pragma unroll
    for (int n = 0; n < 12; n++)
        res += fabsf(A[n][0] * hf0 + A[n][1] * hf1 + A[n][2] * hf2 + A[n][3] * hf3);
    out[OFF_RES + t] = res;
}

extern "C" void kernel_launch(void* const* d_in, const int* in_sizes, int n_in,
                              void* d_out, int out_size, void* d_ws, size_t ws_size,
                              hipStream_t stream) {
    const float* heatmap = (const float*)d_in[0];   // (384,20,64,64)
    const float* proj    = (const float*)d_in[1];   // (64,6,3,4)
    const float* confid  = (const float*)d_in[2];   // (384,20)
    float* out = (float*)d_out;                     // 51200 floats

    hipLaunchKernelGGL(kp_kernel, dim3(NMAPS), dim3(256), 0, stream, heatmap, out);
    hipLaunchKernelGGL(tri_kernel, dim3((BSZ * NJ + 255) / 256), dim3(256), 0, stream,
                       proj, confid, out);
}